// Round 1
// baseline (709.615 us; speedup 1.0000x reference)
//
#include <hip/hip_runtime.h>

#define BATCH 8
#define NBOX 2000
#define NCLS 81
#define NPAD 2048
#define MAX_OUT 300
#define SCORE_T 0.05f
#define IOU_T 0.5f

// ---------------- zero fill ----------------
__global__ void zero_kernel(float* __restrict__ out, int n) {
    int i = blockIdx.x * blockDim.x + threadIdx.x;
    if (i < n) out[i] = 0.0f;
}

// ---------------- prep: softmax fg score/cls + box regression ----------------
__global__ void prep_kernel(const float* __restrict__ deltas,
                            const float* __restrict__ logits,
                            const float* __restrict__ proposals,
                            float4* __restrict__ boxes_out,
                            float* __restrict__ scores_out) {
    int bn = blockIdx.x * blockDim.x + threadIdx.x;
    if (bn >= BATCH * NBOX) return;

    const float* l = logits + (long)bn * NCLS;

    // pass 1: max over all 81
    float M = l[0];
    #pragma unroll 4
    for (int c = 1; c < NCLS; ++c) M = fmaxf(M, l[c]);

    // pass 2: sum exp, and argmax over classes 1..80 (first index wins ties)
    float S = 0.0f;
    float bl = -3.0e38f; int bc = 1;
    #pragma unroll 4
    for (int c = 0; c < NCLS; ++c) {
        float v = l[c];
        S += expf(v - M);
        if (c >= 1 && v > bl) { bl = v; bc = c; }
    }
    float score = expf(bl - M) / S;

    // proposal box [y1,x1,y2,x2,(1)]
    const float* p = proposals + (long)bn * 5;
    float y1 = p[0], x1 = p[1], y2 = p[2], x2 = p[3];
    float h = y2 - y1, w = x2 - x1;
    float cy = (y2 + y1) * 0.5f, cx = (x2 + x1) * 0.5f;

    // selected delta, scaled by BBOX_STD
    const float* d = deltas + ((long)bn * NCLS + bc) * 4;
    float d0 = d[0] * 0.1f, d1 = d[1] * 0.1f, d2 = d[2] * 0.2f, d3 = d[3] * 0.2f;

    cy = cy + d0 * h;
    cx = cx + d1 * w;
    h = h * expf(d2);
    w = w * expf(d3);

    boxes_out[bn] = make_float4(cy - h * 0.5f, cx - w * 0.5f,
                                cy + h * 0.5f, cx + w * 0.5f);
    scores_out[bn] = score;
}

// ---------------- NMS: one block per batch, literal argmax loop ----------------
__global__ __launch_bounds__(256) void nms_kernel(
        const float4* __restrict__ boxes,
        const float* __restrict__ scores,
        const float* __restrict__ logits,
        float* __restrict__ out_boxes,
        float* __restrict__ out_scores,
        float* __restrict__ out_logits) {
    int b = blockIdx.x;
    int tid = threadIdx.x;
    int wid = tid >> 6;
    int lane = tid & 63;

    __shared__ float  s_sc[NPAD];
    __shared__ float4 s_bx[NPAD];
    __shared__ float  s_ar[NPAD];
    __shared__ float  s_redv[4];
    __shared__ int    s_redi[4];
    __shared__ int    s_kept[MAX_OUT];
    __shared__ float  s_ksc[MAX_OUT];

    // init LDS state
    for (int n = tid; n < NPAD; n += 256) {
        if (n < NBOX) {
            float s = scores[b * NBOX + n];
            s_sc[n] = (s > SCORE_T) ? s : -1.0f;
            float4 bx = boxes[b * NBOX + n];
            s_bx[n] = bx;
            s_ar[n] = (bx.z - bx.x) * (bx.w - bx.y);
        } else {
            s_sc[n] = -1.0f;
            s_bx[n] = make_float4(0.f, 0.f, 0.f, 0.f);
            s_ar[n] = 0.0f;
        }
    }
    __syncthreads();

    int count = 0;
    for (int t = 0; t < MAX_OUT; ++t) {
        // local argmax (first-index on tie within a thread: strict >)
        float bv = -2.0f; int bi = 0;
        for (int n = tid; n < NPAD; n += 256) {
            float v = s_sc[n];
            if (v > bv) { bv = v; bi = n; }
        }
        // wave argmax reduce, tie -> smaller index
        #pragma unroll
        for (int off = 32; off; off >>= 1) {
            float ov = __shfl_down(bv, off);
            int   oi = __shfl_down(bi, off);
            if (ov > bv || (ov == bv && oi < bi)) { bv = ov; bi = oi; }
        }
        if (lane == 0) { s_redv[wid] = bv; s_redi[wid] = bi; }
        __syncthreads();
        // all threads combine the 4 wave results redundantly (uniform)
        bv = s_redv[0]; bi = s_redi[0];
        #pragma unroll
        for (int wq = 1; wq < 4; ++wq) {
            float ov = s_redv[wq]; int oi = s_redi[wq];
            if (ov > bv || (ov == bv && oi < bi)) { bv = ov; bi = oi; }
        }
        if (bv <= 0.0f) break;   // everything dead -> remaining rows are zeros

        if (tid == 0) { s_kept[t] = bi; s_ksc[t] = bv; }

        // suppression vs winner
        float4 wb = s_bx[bi];
        float  wa = s_ar[bi];
        for (int n = tid; n < NPAD; n += 256) {
            float4 a = s_bx[n];
            float yy1 = fmaxf(a.x, wb.x), xx1 = fmaxf(a.y, wb.y);
            float yy2 = fminf(a.z, wb.z), xx2 = fminf(a.w, wb.w);
            float inter = fmaxf(yy2 - yy1, 0.0f) * fmaxf(xx2 - xx1, 0.0f);
            float iou = inter / (s_ar[n] + wa - inter + 1e-8f);
            if (iou > IOU_T || n == bi) s_sc[n] = -1.0f;
        }
        count = t + 1;
        __syncthreads();
    }

    // write kept rows (rest of d_out already zeroed)
    for (int k = tid; k < count; k += 256) {
        int idx = s_kept[k];
        float4 bx = s_bx[idx];
        float* ob = out_boxes + ((long)b * MAX_OUT + k) * 5;
        ob[0] = bx.x; ob[1] = bx.y; ob[2] = bx.z; ob[3] = bx.w; ob[4] = 1.0f;
        float* os = out_scores + ((long)b * MAX_OUT + k) * 2;
        os[0] = s_ksc[k]; os[1] = 1.0f;
    }
    for (int e = tid; e < count * NCLS; e += 256) {
        int k = e / NCLS;
        int c = e - k * NCLS;
        int idx = s_kept[k];
        out_logits[((long)b * MAX_OUT + k) * NCLS + c] =
            logits[((long)b * NBOX + idx) * NCLS + c];
    }
}

extern "C" void kernel_launch(void* const* d_in, const int* in_sizes, int n_in,
                              void* d_out, int out_size, void* d_ws, size_t ws_size,
                              hipStream_t stream) {
    const float* deltas    = (const float*)d_in[0];
    const float* logits    = (const float*)d_in[1];
    const float* proposals = (const float*)d_in[2];

    float* out = (float*)d_out;
    float* out_boxes  = out;
    float* out_scores = out + (long)BATCH * MAX_OUT * 5;
    float* out_logits = out + (long)BATCH * MAX_OUT * (5 + 2);

    float4* ws_boxes  = (float4*)d_ws;
    float*  ws_scores = (float*)((char*)d_ws + (size_t)BATCH * NBOX * sizeof(float4));

    int total_out = BATCH * MAX_OUT * (5 + 2 + NCLS);
    zero_kernel<<<(total_out + 255) / 256, 256, 0, stream>>>(out, total_out);
    prep_kernel<<<(BATCH * NBOX + 255) / 256, 256, 0, stream>>>(
        deltas, logits, proposals, ws_boxes, ws_scores);
    nms_kernel<<<BATCH, 256, 0, stream>>>(
        ws_boxes, ws_scores, logits, out_boxes, out_scores, out_logits);
}

// Round 2
// 220.144 us; speedup vs baseline: 3.2234x; 3.2234x over previous
//
#include <hip/hip_runtime.h>

#define BATCH 8
#define NBOX 2000
#define NCLS 81
#define NPAD 2048
#define MAX_OUT 300
#define SCORE_T 0.05f
#define IOU_T 0.5f
#define SORT_THREADS 1024

// ---------------- prep: softmax fg score/cls + box regression ----------------
__global__ void prep_kernel(const float* __restrict__ deltas,
                            const float* __restrict__ logits,
                            const float* __restrict__ proposals,
                            float4* __restrict__ boxes_out,
                            float* __restrict__ scores_out) {
    int bn = blockIdx.x * blockDim.x + threadIdx.x;
    if (bn >= BATCH * NBOX) return;

    const float* l = logits + (long)bn * NCLS;

    float M = l[0];
    #pragma unroll 4
    for (int c = 1; c < NCLS; ++c) M = fmaxf(M, l[c]);

    float S = 0.0f;
    float bl = -3.0e38f; int bc = 1;
    #pragma unroll 4
    for (int c = 0; c < NCLS; ++c) {
        float v = l[c];
        S += expf(v - M);
        if (c >= 1 && v > bl) { bl = v; bc = c; }
    }
    float score = expf(bl - M) / S;

    const float* p = proposals + (long)bn * 5;
    float y1 = p[0], x1 = p[1], y2 = p[2], x2 = p[3];
    float h = y2 - y1, w = x2 - x1;
    float cy = (y2 + y1) * 0.5f, cx = (x2 + x1) * 0.5f;

    const float* d = deltas + ((long)bn * NCLS + bc) * 4;
    float d0 = d[0] * 0.1f, d1 = d[1] * 0.1f, d2 = d[2] * 0.2f, d3 = d[3] * 0.2f;

    cy = cy + d0 * h;
    cx = cx + d1 * w;
    h = h * expf(d2);
    w = w * expf(d3);

    boxes_out[bn] = make_float4(cy - h * 0.5f, cx - w * 0.5f,
                                cy + h * 0.5f, cx + w * 0.5f);
    scores_out[bn] = score;
}

// ------- NMS: sort-once (bitonic) + wave-0 blocked greedy walk -------
__global__ __launch_bounds__(SORT_THREADS) void nms_kernel(
        const float4* __restrict__ boxes,
        const float* __restrict__ scores,
        const float* __restrict__ logits,
        float* __restrict__ out_boxes,
        float* __restrict__ out_scores,
        float* __restrict__ out_logits) {
    int b = blockIdx.x;
    int tid = threadIdx.x;

    __shared__ unsigned long long s_key[NPAD];   // 16 KB
    __shared__ float4 s_bx[NPAD];                // 32 KB (sorted boxes)
    __shared__ float4 s_kbox[MAX_OUT];
    __shared__ float  s_karea[MAX_OUT];
    __shared__ float  s_kscore[MAX_OUT];
    __shared__ int    s_kidx[MAX_OUT];
    __shared__ int    s_L;
    __shared__ int    s_kcount;

    if (tid == 0) { s_L = 0; s_kcount = 0; }

    // build sort keys: high32 = score float bits (positive -> monotone),
    // low32 = ~index so equal scores order by ascending original index
    for (int r = tid; r < NPAD; r += SORT_THREADS) {
        unsigned long long key = 0ull;
        if (r < NBOX) {
            float s = scores[b * NBOX + r];
            unsigned int fb = __float_as_uint(s);
            key = ((unsigned long long)fb << 32) |
                  (unsigned long long)(0xFFFFFFFFu - (unsigned)r);
        }
        s_key[r] = key;
    }
    __syncthreads();

    // bitonic sort, descending
    for (int k = 2; k <= NPAD; k <<= 1) {
        for (int j = k >> 1; j > 0; j >>= 1) {
            for (int i = tid; i < NPAD; i += SORT_THREADS) {
                int l = i ^ j;
                if (l > i) {
                    unsigned long long a = s_key[i], c = s_key[l];
                    bool up = ((i & k) == 0);
                    if ((a < c) == up) { s_key[i] = c; s_key[l] = a; }
                }
            }
            __syncthreads();
        }
    }

    // gather boxes in sorted order; find alive-prefix length L (scores > SCORE_T)
    for (int r = tid; r < NPAD; r += SORT_THREADS) {
        unsigned long long key = s_key[r];
        unsigned int fb = (unsigned int)(key >> 32);
        float sc = __uint_as_float(fb);
        float4 bx = make_float4(0.f, 0.f, 0.f, 0.f);
        if (fb) {
            int orig = (int)(0xFFFFFFFFu - (unsigned int)key);
            bx = boxes[b * NBOX + orig];
        }
        s_bx[r] = bx;
        float scn = 0.0f;
        if (r + 1 < NPAD) {
            unsigned int fbn = (unsigned int)(s_key[r + 1] >> 32);
            scn = __uint_as_float(fbn);
        }
        if (sc > SCORE_T && !(scn > SCORE_T)) s_L = r + 1;
    }
    __syncthreads();

    // wave-0 greedy walk over sorted candidates, 64 at a time
    if (tid < 64) {
        int lane = tid;
        int L = s_L;
        int kept = 0;
        int nblk = (L + 63) >> 6;
        for (int blk = 0; blk < nblk && kept < MAX_OUT; ++blk) {
            int r = (blk << 6) + lane;          // r < NPAD always (L <= 2000)
            bool valid = (r < L);
            float4 bx = s_bx[r];
            float area = (bx.z - bx.x) * (bx.w - bx.y);
            unsigned long long key = s_key[r];
            float myscore = __uint_as_float((unsigned int)(key >> 32));
            int myorig = (int)(0xFFFFFFFFu - (unsigned int)key);

            // check this chunk's candidates against all previously-kept boxes
            bool sup = false;
            for (int k = 0; k < kept; ++k) {
                float4 kb = s_kbox[k];
                float ka = s_karea[k];
                float yy1 = fmaxf(bx.x, kb.x), xx1 = fmaxf(bx.y, kb.y);
                float yy2 = fminf(bx.z, kb.z), xx2 = fminf(bx.w, kb.w);
                float inter = fmaxf(yy2 - yy1, 0.f) * fmaxf(xx2 - xx1, 0.f);
                float iou = inter / (area + ka - inter + 1e-8f);
                sup = sup || (iou > IOU_T);
            }

            unsigned long long live = __ballot(valid && !sup);
            // resolve within-chunk order exactly (greedy, score-descending)
            while (live && kept < MAX_OUT) {
                int w = (int)__builtin_ctzll(live);
                float wy1 = __shfl(bx.x, w);
                float wx1 = __shfl(bx.y, w);
                float wy2 = __shfl(bx.z, w);
                float wx2 = __shfl(bx.w, w);
                float wa  = __shfl(area, w);
                if (lane == w) {
                    s_kbox[kept] = bx;
                    s_karea[kept] = area;
                    s_kscore[kept] = myscore;
                    s_kidx[kept] = myorig;
                }
                kept++;
                float yy1 = fmaxf(bx.x, wy1), xx1 = fmaxf(bx.y, wx1);
                float yy2 = fminf(bx.z, wy2), xx2 = fminf(bx.w, wx2);
                float inter = fmaxf(yy2 - yy1, 0.f) * fmaxf(xx2 - xx1, 0.f);
                float iou = inter / (area + wa - inter + 1e-8f);
                live &= ~__ballot(iou > IOU_T);
            }
        }
        if (lane == 0) s_kcount = kept;
    }
    __syncthreads();

    // write full outputs (zeros beyond kept count)
    int kc = s_kcount;
    for (int e = tid; e < MAX_OUT * 5; e += SORT_THREADS) {
        int k = e / 5, c = e - k * 5;
        float v = 0.f;
        if (k < kc) {
            float4 bx = s_kbox[k];
            v = (c == 0) ? bx.x : (c == 1) ? bx.y : (c == 2) ? bx.z
                : (c == 3) ? bx.w : 1.0f;
        }
        out_boxes[(long)b * MAX_OUT * 5 + e] = v;
    }
    for (int e = tid; e < MAX_OUT * 2; e += SORT_THREADS) {
        int k = e >> 1, c = e & 1;
        float v = 0.f;
        if (k < kc) v = c ? 1.0f : s_kscore[k];
        out_scores[(long)b * MAX_OUT * 2 + e] = v;
    }
    for (int e = tid; e < MAX_OUT * NCLS; e += SORT_THREADS) {
        int k = e / NCLS, c = e - k * NCLS;
        float v = 0.f;
        if (k < kc) v = logits[((long)b * NBOX + s_kidx[k]) * NCLS + c];
        out_logits[(long)b * MAX_OUT * NCLS + e] = v;
    }
}

extern "C" void kernel_launch(void* const* d_in, const int* in_sizes, int n_in,
                              void* d_out, int out_size, void* d_ws, size_t ws_size,
                              hipStream_t stream) {
    const float* deltas    = (const float*)d_in[0];
    const float* logits    = (const float*)d_in[1];
    const float* proposals = (const float*)d_in[2];

    float* out = (float*)d_out;
    float* out_boxes  = out;
    float* out_scores = out + (long)BATCH * MAX_OUT * 5;
    float* out_logits = out + (long)BATCH * MAX_OUT * (5 + 2);

    float4* ws_boxes  = (float4*)d_ws;
    float*  ws_scores = (float*)((char*)d_ws + (size_t)BATCH * NBOX * sizeof(float4));

    prep_kernel<<<(BATCH * NBOX + 255) / 256, 256, 0, stream>>>(
        deltas, logits, proposals, ws_boxes, ws_scores);
    nms_kernel<<<BATCH, SORT_THREADS, 0, stream>>>(
        ws_boxes, ws_scores, logits, out_boxes, out_scores, out_logits);
}